// Round 1
// baseline (671.390 us; speedup 1.0000x reference)
//
#include <hip/hip_runtime.h>
#include <stdint.h>

typedef unsigned short u16;
typedef float f32x4 __attribute__((ext_vector_type(4)));
typedef short s16x8 __attribute__((ext_vector_type(8)));

constexpr int B  = 8;
constexpr int S  = 1024;
constexpr int DM = 1024;
constexpr int H  = 16;
constexpr int M  = B * S;          // 8192 rows
constexpr float NEGINF = -1e9f;

__device__ __forceinline__ u16 f2bf(float f) {
    union { float f; uint32_t u; } v; v.f = f;
    uint32_t u = v.u;
    uint32_t r = 0x7FFFu + ((u >> 16) & 1u);   // round-to-nearest-even
    return (u16)((u + r) >> 16);
}

// ---------------- fp32 -> bf16 elementwise ----------------
__global__ void cvt_f32_bf16(const float* __restrict__ in, u16* __restrict__ out) {
    int i = (blockIdx.x * 256 + threadIdx.x) * 4;
    float4 v = *(const float4*)(in + i);
    ushort4 o;
    o.x = f2bf(v.x); o.y = f2bf(v.y); o.z = f2bf(v.z); o.w = f2bf(v.w);
    *(ushort4*)(out + i) = o;
}

// ---------------- W[k][n] fp32 -> Wt[n][k] bf16 ----------------
__global__ void transpose_w(const float* __restrict__ W, u16* __restrict__ Wt) {
    __shared__ float tile[32][33];
    int n0 = blockIdx.x * 32, k0 = blockIdx.y * 32;
    int tx = threadIdx.x & 31, ty = threadIdx.x >> 5;   // 32 x 8
#pragma unroll
    for (int r = 0; r < 4; ++r)
        tile[ty + r*8][tx] = W[(size_t)(k0 + ty + r*8) * DM + n0 + tx];
    __syncthreads();
#pragma unroll
    for (int r = 0; r < 4; ++r)
        Wt[(size_t)(n0 + ty + r*8) * DM + k0 + tx] = f2bf(tile[tx][ty + r*8]);
}

// ---------------- GEMM: C[M x 1024] = A[M x 1024] * Bt[1024 x 1024]^T ----------------
// 128x128 tile, BK=32, 4 waves (each 64x64 = 4x4 fragments of 16x16x32 bf16 MFMA)
// EPI 0: C bf16 row-major.  EPI 1: V transposed write -> Vt[(b*16+h)*64+d][s].
// EPI 2: fp32 C + residual.
template<int EPI>
__global__ __launch_bounds__(256, 2)
void gemm_bt(const u16* __restrict__ A, const u16* __restrict__ Bt,
             void* __restrict__ Cv, const float* __restrict__ resid)
{
    __shared__ u16 As[128 * 40];   // +8 elem pad per row vs 32
    __shared__ u16 Bs[128 * 40];
    const int m0 = blockIdx.y * 128;
    const int n0 = blockIdx.x * 128;
    const int t = threadIdx.x;
    const int lane = t & 63;
    const int wid = t >> 6;
    const int wm = (wid >> 1) * 64;
    const int wn = (wid & 1) * 64;
    const int lr = lane & 15;
    const int lg = lane >> 4;

    const int srow = t >> 2;          // 0..63
    const int sch  = (t & 3) * 8;     // 0,8,16,24 (elements)

    const u16* Ag0 = A  + (size_t)(m0 + srow) * 1024 + sch;
    const u16* Ag1 = A  + (size_t)(m0 + srow + 64) * 1024 + sch;
    const u16* Bg0 = Bt + (size_t)(n0 + srow) * 1024 + sch;
    const u16* Bg1 = Bt + (size_t)(n0 + srow + 64) * 1024 + sch;
    u16* Aw0 = As + srow * 40 + sch;
    u16* Aw1 = As + (srow + 64) * 40 + sch;
    u16* Bw0 = Bs + srow * 40 + sch;
    u16* Bw1 = Bs + (srow + 64) * 40 + sch;

    f32x4 acc[4][4] = {};

    for (int kt = 0; kt < 32; ++kt) {
        const int ko = kt * 32;
        uint4 a0 = *(const uint4*)(Ag0 + ko);
        uint4 a1 = *(const uint4*)(Ag1 + ko);
        uint4 b0 = *(const uint4*)(Bg0 + ko);
        uint4 b1 = *(const uint4*)(Bg1 + ko);
        __syncthreads();
        *(uint4*)Aw0 = a0; *(uint4*)Aw1 = a1;
        *(uint4*)Bw0 = b0; *(uint4*)Bw1 = b1;
        __syncthreads();
        s16x8 af[4], bfr[4];
#pragma unroll
        for (int m = 0; m < 4; ++m)
            af[m] = *(const s16x8*)(As + (wm + m*16 + lr) * 40 + lg * 8);
#pragma unroll
        for (int n = 0; n < 4; ++n)
            bfr[n] = *(const s16x8*)(Bs + (wn + n*16 + lr) * 40 + lg * 8);
#pragma unroll
        for (int m = 0; m < 4; ++m)
#pragma unroll
            for (int n = 0; n < 4; ++n)
                acc[m][n] = __builtin_amdgcn_mfma_f32_16x16x32_bf16(af[m], bfr[n], acc[m][n], 0, 0, 0);
    }

#pragma unroll
    for (int m = 0; m < 4; ++m) {
#pragma unroll
        for (int n = 0; n < 4; ++n) {
            const int rg0 = m0 + wm + m*16 + lg*4;   // D row = (lane>>4)*4 + reg
            const int cg  = n0 + wn + n*16 + lr;     // D col = lane&15
            if constexpr (EPI == 0) {
                u16* C = (u16*)Cv;
#pragma unroll
                for (int r = 0; r < 4; ++r)
                    C[(size_t)(rg0 + r) * 1024 + cg] = f2bf(acc[m][n][r]);
            } else if constexpr (EPI == 1) {
                u16* C = (u16*)Cv;
                const int bb = rg0 >> 10;
                const int s0 = rg0 & 1023;
                const int hh = cg >> 6;
                const int dd = cg & 63;
                ushort4 pk;
                pk.x = f2bf(acc[m][n][0]); pk.y = f2bf(acc[m][n][1]);
                pk.z = f2bf(acc[m][n][2]); pk.w = f2bf(acc[m][n][3]);
                *(ushort4*)(C + (size_t)((bb*16 + hh)*64 + dd) * 1024 + s0) = pk;
            } else {
                float* C = (float*)Cv;
#pragma unroll
                for (int r = 0; r < 4; ++r) {
                    size_t idx = (size_t)(rg0 + r) * 1024 + cg;
                    C[idx] = acc[m][n][r] + resid[idx];
                }
            }
        }
    }
}

// ---------------- scores + softmax -> attn (fp32, full matrix) ----------------
// block: (h, qtile of 32 rows, b); 4 waves, wave w owns cols [w*256, w*256+256)
__global__ __launch_bounds__(256, 2)
void attn_scores(const u16* __restrict__ Qp, const u16* __restrict__ Kp,
                 const void* __restrict__ maskp, float* __restrict__ attn)
{
    const int h  = blockIdx.x;
    const int q0 = blockIdx.y * 32;
    const int b  = blockIdx.z;
    const int t = threadIdx.x;
    const int lane = t & 63;
    const int w = t >> 6;
    const int lr = lane & 15;
    const int lg = lane >> 4;

    __shared__ float redA[4][32];
    __shared__ float redB[4][32];

    // detect mask dtype: int32 (values 0/1 -> OR<=1) vs packed bytes (OR has high bytes)
    uint32_t orv = 0;
    const uint32_t* mw = (const uint32_t*)maskp;
#pragma unroll
    for (int i = 0; i < 64; ++i) orv |= mw[i];
    const bool mask_bytes = (orv > 1u);

    s16x8 qf[2][2];
#pragma unroll
    for (int mq = 0; mq < 2; ++mq)
#pragma unroll
        for (int ks = 0; ks < 2; ++ks)
            qf[mq][ks] = *(const s16x8*)(Qp + (size_t)(b*S + q0 + mq*16 + lr) * DM + h*64 + ks*32 + lg*8);

    f32x4 acc[2][16];
#pragma unroll
    for (int nk = 0; nk < 16; ++nk) {
        const int sk = w*256 + nk*16 + lr;
        const u16* kb = Kp + (size_t)(b*S + sk) * DM + h*64 + lg*8;
        s16x8 kf0 = *(const s16x8*)(kb);
        s16x8 kf1 = *(const s16x8*)(kb + 32);
        f32x4 c0 = {};
        c0 = __builtin_amdgcn_mfma_f32_16x16x32_bf16(qf[0][0], kf0, c0, 0, 0, 0);
        c0 = __builtin_amdgcn_mfma_f32_16x16x32_bf16(qf[0][1], kf1, c0, 0, 0, 0);
        acc[0][nk] = c0;
        f32x4 c1 = {};
        c1 = __builtin_amdgcn_mfma_f32_16x16x32_bf16(qf[1][0], kf0, c1, 0, 0, 0);
        c1 = __builtin_amdgcn_mfma_f32_16x16x32_bf16(qf[1][1], kf1, c1, 0, 0, 0);
        acc[1][nk] = c1;
    }

    // scale + mask
    const size_t mbase = (size_t)b * S * S;
#pragma unroll
    for (int mq = 0; mq < 2; ++mq) {
#pragma unroll
        for (int r = 0; r < 4; ++r) {
            const int q = q0 + mq*16 + lg*4 + r;
            const size_t roff = mbase + (size_t)q * S + w*256 + lr;
#pragma unroll
            for (int nk = 0; nk < 16; ++nk) {
                int mv;
                if (mask_bytes) mv = ((const uint8_t*)maskp)[roff + nk*16];
                else            mv = ((const int*)maskp)[roff + nk*16];
                float s = acc[mq][nk][r] * 0.125f;
                acc[mq][nk][r] = mv ? NEGINF : s;
            }
        }
    }

    // row max (reduce over nk in-lane, then across the 16 col-lanes)
    float rmax[2][4];
#pragma unroll
    for (int mq = 0; mq < 2; ++mq)
#pragma unroll
        for (int r = 0; r < 4; ++r) {
            float m = acc[mq][0][r];
#pragma unroll
            for (int nk = 1; nk < 16; ++nk) m = fmaxf(m, acc[mq][nk][r]);
#pragma unroll
            for (int d = 1; d < 16; d <<= 1) m = fmaxf(m, __shfl_xor(m, d, 64));
            rmax[mq][r] = m;
        }
    if (lr == 0) {
#pragma unroll
        for (int mq = 0; mq < 2; ++mq)
#pragma unroll
            for (int r = 0; r < 4; ++r)
                redA[w][mq*16 + lg*4 + r] = rmax[mq][r];
    }
    __syncthreads();
#pragma unroll
    for (int mq = 0; mq < 2; ++mq)
#pragma unroll
        for (int r = 0; r < 4; ++r) {
            const int row = mq*16 + lg*4 + r;
            rmax[mq][r] = fmaxf(fmaxf(redA[0][row], redA[1][row]),
                                fmaxf(redA[2][row], redA[3][row]));
        }

    // exp + row sum
#pragma unroll
    for (int mq = 0; mq < 2; ++mq)
#pragma unroll
        for (int r = 0; r < 4; ++r) {
            float sme = 0.f;
#pragma unroll
            for (int nk = 0; nk < 16; ++nk) {
                float p = __expf(acc[mq][nk][r] - rmax[mq][r]);
                acc[mq][nk][r] = p;
                sme += p;
            }
#pragma unroll
            for (int d = 1; d < 16; d <<= 1) sme += __shfl_xor(sme, d, 64);
            if (lr == 0) redB[w][mq*16 + lg*4 + r] = sme;
        }
    __syncthreads();

    float* ab = attn + (size_t)(b*H + h) * S * S;
#pragma unroll
    for (int mq = 0; mq < 2; ++mq)
#pragma unroll
        for (int r = 0; r < 4; ++r) {
            const int row = mq*16 + lg*4 + r;
            const float inv = 1.0f / (redB[0][row] + redB[1][row] + redB[2][row] + redB[3][row]);
            float* arow = ab + (size_t)(q0 + row) * S + w*256 + lr;
#pragma unroll
            for (int nk = 0; nk < 16; ++nk)
                arow[nk*16] = acc[mq][nk][r] * inv;
        }
}

// ---------------- context = attn @ V ----------------
// block: (qtile of 64 rows, h, b); wave w owns 16 q-rows, full k=1024, d=64
__global__ __launch_bounds__(256, 2)
void attn_pv(const float* __restrict__ attn, const u16* __restrict__ Vt,
             u16* __restrict__ ctx)
{
    const int qt = blockIdx.x;
    const int h  = blockIdx.y;
    const int b  = blockIdx.z;
    const int t = threadIdx.x;
    const int lane = t & 63;
    const int w = t >> 6;
    const int lr = lane & 15;
    const int lg = lane >> 4;

    const int q = qt*64 + w*16 + lr;                       // A-frag row = lane&15
    const float* arow = attn + ((size_t)(b*H + h) * S + q) * S;
    const u16* vb = Vt + (size_t)(b*H + h) * 64 * S;

    f32x4 acc[4] = {};
    for (int kt = 0; kt < 32; ++kt) {
        const int k0 = kt*32 + lg*8;
        float4 p0 = *(const float4*)(arow + k0);
        float4 p1 = *(const float4*)(arow + k0 + 4);
        s16x8 af;
        af[0] = (short)f2bf(p0.x); af[1] = (short)f2bf(p0.y);
        af[2] = (short)f2bf(p0.z); af[3] = (short)f2bf(p0.w);
        af[4] = (short)f2bf(p1.x); af[5] = (short)f2bf(p1.y);
        af[6] = (short)f2bf(p1.z); af[7] = (short)f2bf(p1.w);
#pragma unroll
        for (int nd = 0; nd < 4; ++nd) {
            s16x8 vf = *(const s16x8*)(vb + (size_t)(nd*16 + lr) * S + k0);
            acc[nd] = __builtin_amdgcn_mfma_f32_16x16x32_bf16(af, vf, acc[nd], 0, 0, 0);
        }
    }
#pragma unroll
    for (int nd = 0; nd < 4; ++nd)
#pragma unroll
        for (int r = 0; r < 4; ++r)
            ctx[(size_t)(b*S + qt*64 + w*16 + lg*4 + r) * DM + h*64 + nd*16 + lr] = f2bf(acc[nd][r]);
}

// ---------------- LayerNorm over rows of 1024 ----------------
__global__ __launch_bounds__(256)
void layernorm(const float* __restrict__ x, const float* __restrict__ gamma,
               const float* __restrict__ beta, float* __restrict__ out)
{
    const int row = blockIdx.x;
    const int t = threadIdx.x;
    const float* xr = x + (size_t)row * DM;
    float4 v = *(const float4*)(xr + t*4);
    float s  = v.x + v.y + v.z + v.w;
    float s2 = v.x*v.x + v.y*v.y + v.z*v.z + v.w*v.w;
#pragma unroll
    for (int d = 1; d < 64; d <<= 1) {
        s  += __shfl_xor(s,  d, 64);
        s2 += __shfl_xor(s2, d, 64);
    }
    __shared__ float ls[4], ls2[4];
    if ((t & 63) == 0) { ls[t >> 6] = s; ls2[t >> 6] = s2; }
    __syncthreads();
    s  = ls[0] + ls[1] + ls[2] + ls[3];
    s2 = ls2[0] + ls2[1] + ls2[2] + ls2[3];
    const float mu  = s * (1.0f / DM);
    const float var = s2 * (1.0f / DM) - mu * mu;
    const float rs  = rsqrtf(var + 1e-5f);
    float4 g  = *(const float4*)(gamma + t*4);
    float4 bb = *(const float4*)(beta  + t*4);
    float4 o;
    o.x = (v.x - mu) * rs * g.x + bb.x;
    o.y = (v.y - mu) * rs * g.y + bb.y;
    o.z = (v.z - mu) * rs * g.z + bb.z;
    o.w = (v.w - mu) * rs * g.w + bb.w;
    *(float4*)(out + (size_t)row * DM + t*4) = o;
}

extern "C" void kernel_launch(void* const* d_in, const int* in_sizes, int n_in,
                              void* d_out, int out_size, void* d_ws, size_t ws_size,
                              hipStream_t stream) {
    const float* Qin  = (const float*)d_in[0];
    const float* Kin  = (const float*)d_in[1];
    const float* Vin  = (const float*)d_in[2];
    const void*  mask = d_in[3];
    const float* Wq   = (const float*)d_in[4];
    const float* Wk   = (const float*)d_in[5];
    const float* Wv   = (const float*)d_in[6];
    const float* Wfc  = (const float*)d_in[7];
    const float* gam  = (const float*)d_in[8];
    const float* bet  = (const float*)d_in[9];

    float* out  = (float*)d_out;
    float* attn = (float*)d_out + (size_t)M * DM;

    char* ws = (char*)d_ws;
    constexpr size_t SZ_X = (size_t)M * DM * 2;    // 16 MiB
    constexpr size_t SZ_W = (size_t)DM * DM * 2;   // 2 MiB
    u16* Xq  = (u16*)(ws);
    u16* Xk  = (u16*)(ws + SZ_X);
    u16* Xv  = (u16*)(ws + 2*SZ_X);
    u16* WqT = (u16*)(ws + 3*SZ_X);
    u16* WkT = (u16*)(ws + 3*SZ_X + SZ_W);
    u16* WvT = (u16*)(ws + 3*SZ_X + 2*SZ_W);
    u16* WfT = (u16*)(ws + 3*SZ_X + 3*SZ_W);
    u16* Qp  = (u16*)(ws + 3*SZ_X + 4*SZ_W);
    u16* Kp  = (u16*)(ws + 4*SZ_X + 4*SZ_W);
    u16* Vt  = (u16*)(ws + 5*SZ_X + 4*SZ_W);
    // aliases onto dead buffers (Xq/Xk dead after projections; Xv dead too):
    float* preLN = (float*)(ws);               // 32 MiB over Xq+Xk
    u16*   Ctx   = (u16*)(ws + 2*SZ_X);        // 16 MiB over Xv

    dim3 blk(256);
    cvt_f32_bf16<<<dim3(M * DM / 1024), blk, 0, stream>>>(Qin, Xq);
    cvt_f32_bf16<<<dim3(M * DM / 1024), blk, 0, stream>>>(Kin, Xk);
    cvt_f32_bf16<<<dim3(M * DM / 1024), blk, 0, stream>>>(Vin, Xv);
    transpose_w<<<dim3(32, 32), blk, 0, stream>>>(Wq,  WqT);
    transpose_w<<<dim3(32, 32), blk, 0, stream>>>(Wk,  WkT);
    transpose_w<<<dim3(32, 32), blk, 0, stream>>>(Wv,  WvT);
    transpose_w<<<dim3(32, 32), blk, 0, stream>>>(Wfc, WfT);

    gemm_bt<0><<<dim3(8, 64), blk, 0, stream>>>(Xq, WqT, Qp, nullptr);
    gemm_bt<0><<<dim3(8, 64), blk, 0, stream>>>(Xk, WkT, Kp, nullptr);
    gemm_bt<1><<<dim3(8, 64), blk, 0, stream>>>(Xv, WvT, Vt, nullptr);

    attn_scores<<<dim3(H, S / 32, B), blk, 0, stream>>>(Qp, Kp, mask, attn);
    attn_pv<<<dim3(S / 64, H, B), blk, 0, stream>>>(attn, Vt, Ctx);

    gemm_bt<2><<<dim3(8, 64), blk, 0, stream>>>(Ctx, WfT, preLN, Qin);
    layernorm<<<dim3(M), blk, 0, stream>>>(preLN, gam, bet, out);
}

// Round 2
// 568.258 us; speedup vs baseline: 1.1815x; 1.1815x over previous
//
#include <hip/hip_runtime.h>
#include <stdint.h>

typedef unsigned short u16;
typedef float f32x4 __attribute__((ext_vector_type(4)));
typedef short s16x8 __attribute__((ext_vector_type(8)));

constexpr int B  = 8;
constexpr int S  = 1024;
constexpr int DM = 1024;
constexpr int H  = 16;
constexpr int M  = B * S;          // 8192 rows
constexpr float NEGINF = -1e9f;

__device__ __forceinline__ u16 f2bf(float f) {
    union { float f; uint32_t u; } v; v.f = f;
    uint32_t u = v.u;
    uint32_t r = 0x7FFFu + ((u >> 16) & 1u);   // round-to-nearest-even
    return (u16)((u + r) >> 16);
}

// async global->LDS 16B (m97 form): LDS dest = wave-uniform base + lane*16
__device__ __forceinline__ void gload16(const u16* g, u16* l) {
    __builtin_amdgcn_global_load_lds(
        (const __attribute__((address_space(1))) unsigned int*)g,
        (__attribute__((address_space(3))) unsigned int*)l, 16, 0, 0);
}

// ---------------- fp32 -> bf16, all three inputs in one launch ----------------
__global__ void cvt_all(const float* __restrict__ q, const float* __restrict__ k,
                        const float* __restrict__ v,
                        u16* __restrict__ xq, u16* __restrict__ xk, u16* __restrict__ xv) {
    const float* in; u16* out;
    if (blockIdx.y == 0)      { in = q; out = xq; }
    else if (blockIdx.y == 1) { in = k; out = xk; }
    else                      { in = v; out = xv; }
    int i = (blockIdx.x * 256 + threadIdx.x) * 4;
    float4 val = *(const float4*)(in + i);
    ushort4 o;
    o.x = f2bf(val.x); o.y = f2bf(val.y); o.z = f2bf(val.z); o.w = f2bf(val.w);
    *(ushort4*)(out + i) = o;
}

// ---------------- W[k][n] fp32 -> Wt[n][k] bf16, all four weights ----------------
__global__ void transpose_all(const float* __restrict__ w0, const float* __restrict__ w1,
                              const float* __restrict__ w2, const float* __restrict__ w3,
                              u16* __restrict__ o0, u16* __restrict__ o1,
                              u16* __restrict__ o2, u16* __restrict__ o3) {
    const float* W; u16* Wt;
    switch (blockIdx.z) {
        case 0:  W = w0; Wt = o0; break;
        case 1:  W = w1; Wt = o1; break;
        case 2:  W = w2; Wt = o2; break;
        default: W = w3; Wt = o3; break;
    }
    __shared__ float tile[32][33];
    int n0 = blockIdx.x * 32, k0 = blockIdx.y * 32;
    int tx = threadIdx.x & 31, ty = threadIdx.x >> 5;   // 32 x 8
#pragma unroll
    for (int r = 0; r < 4; ++r)
        tile[ty + r*8][tx] = W[(size_t)(k0 + ty + r*8) * DM + n0 + tx];
    __syncthreads();
#pragma unroll
    for (int r = 0; r < 4; ++r)
        Wt[(size_t)(n0 + ty + r*8) * DM + k0 + tx] = f2bf(tile[tx][ty + r*8]);
}

// ---------------- GEMM: C[M x 1024] = A[M x 1024] * Bt[1024 x 1024]^T ----------------
// m97 structure: 128x128 tile, BK=32, global_load_lds width=16, linear LDS.
// EPI 0: C bf16 row-major.  EPI 1: V transposed -> Vt[(b*16+h)*64+d][s].  EPI 2: fp32 + resid.
template<int EPI>
__global__ __launch_bounds__(256, 2)
void gemm_bt(const u16* __restrict__ A, const u16* __restrict__ Bt,
             void* __restrict__ Cv, const float* __restrict__ resid)
{
    __shared__ u16 As[128 * 32];
    __shared__ u16 Bs[128 * 32];
    const int m0 = blockIdx.y * 128;
    const int n0 = blockIdx.x * 128;
    const int t = threadIdx.x;
    const int lane = t & 63;
    const int wid = t >> 6;
    const int wm = (wid >> 1) * 64;
    const int wn = (wid & 1) * 64;
    const int lr = lane & 15;
    const int lg = lane >> 4;

    // thread t stages 16B: LDS element t*8 == row t>>2, col (t&3)*8 of [128][32]
    const u16* Ag = A  + (size_t)(m0 + (t >> 2)) * 1024 + (t & 3) * 8;
    const u16* Bg = Bt + (size_t)(n0 + (t >> 2)) * 1024 + (t & 3) * 8;
    u16* Al = As + t * 8;
    u16* Bl = Bs + t * 8;

    f32x4 acc[4][4] = {};

    for (int kt = 0; kt < 32; ++kt) {
        const int ko = kt * 32;
        __syncthreads();                       // previous compute done
        gload16(Ag + ko,            Al);
        gload16(Ag + 64*1024 + ko,  Al + 64*32);
        gload16(Bg + ko,            Bl);
        gload16(Bg + 64*1024 + ko,  Bl + 64*32);
        __syncthreads();                       // barrier drains vmcnt -> LDS ready
        s16x8 af[4], bfr[4];
#pragma unroll
        for (int m = 0; m < 4; ++m)
            af[m] = *(const s16x8*)(As + (wm + m*16 + lr) * 32 + lg * 8);
#pragma unroll
        for (int n = 0; n < 4; ++n)
            bfr[n] = *(const s16x8*)(Bs + (wn + n*16 + lr) * 32 + lg * 8);
#pragma unroll
        for (int m = 0; m < 4; ++m)
#pragma unroll
            for (int n = 0; n < 4; ++n)
                acc[m][n] = __builtin_amdgcn_mfma_f32_16x16x32_bf16(af[m], bfr[n], acc[m][n], 0, 0, 0);
    }

#pragma unroll
    for (int m = 0; m < 4; ++m) {
#pragma unroll
        for (int n = 0; n < 4; ++n) {
            const int rg0 = m0 + wm + m*16 + lg*4;   // D row = (lane>>4)*4 + reg
            const int cg  = n0 + wn + n*16 + lr;     // D col = lane&15
            if constexpr (EPI == 0) {
                u16* C = (u16*)Cv;
#pragma unroll
                for (int r = 0; r < 4; ++r)
                    C[(size_t)(rg0 + r) * 1024 + cg] = f2bf(acc[m][n][r]);
            } else if constexpr (EPI == 1) {
                u16* C = (u16*)Cv;
                const int bb = rg0 >> 10;
                const int s0 = rg0 & 1023;
                const int hh = cg >> 6;
                const int dd = cg & 63;
                ushort4 pk;
                pk.x = f2bf(acc[m][n][0]); pk.y = f2bf(acc[m][n][1]);
                pk.z = f2bf(acc[m][n][2]); pk.w = f2bf(acc[m][n][3]);
                *(ushort4*)(C + (size_t)((bb*16 + hh)*64 + dd) * 1024 + s0) = pk;
            } else {
                float* C = (float*)Cv;
#pragma unroll
                for (int r = 0; r < 4; ++r) {
                    size_t idx = (size_t)(rg0 + r) * 1024 + cg;
                    C[idx] = acc[m][n][r] + resid[idx];
                }
            }
        }
    }
}

// ---------------- fused scores + softmax + attn-write + PV ----------------
// block: (h, qtile of 32 rows, b); 4 waves. Scores phase: wave w owns cols
// [w*256, w*256+256). PV phase: wave w owns d-slice [w*16, w*16+16), full k.
__global__ __launch_bounds__(256, 2)
void attn_fused(const u16* __restrict__ Qp, const u16* __restrict__ Kp,
                const void* __restrict__ maskp, const u16* __restrict__ Vt,
                float* __restrict__ attn, u16* __restrict__ ctx)
{
    const int h  = blockIdx.x;
    const int q0 = blockIdx.y * 32;
    const int b  = blockIdx.z;
    const int t = threadIdx.x;
    const int lane = t & 63;
    const int w = t >> 6;
    const int lr = lane & 15;
    const int lg = lane >> 4;

    constexpr int PLD = 1032;          // stride: 516 dwords == 4 mod 32 -> b128 reads 2-way (free)
    __shared__ u16 Plds[32 * PLD];     // ~66 KB
    __shared__ float redA[4][32];
    __shared__ float redB[4][32];

    // detect mask dtype: int32 (values 0/1 -> OR<=1) vs packed bytes
    uint32_t orv = 0;
    const uint32_t* mw = (const uint32_t*)maskp;
#pragma unroll
    for (int i = 0; i < 64; ++i) orv |= mw[i];
    const bool mask_bytes = (orv > 1u);

    s16x8 qf[2][2];
#pragma unroll
    for (int mq = 0; mq < 2; ++mq)
#pragma unroll
        for (int ks = 0; ks < 2; ++ks)
            qf[mq][ks] = *(const s16x8*)(Qp + (size_t)(b*S + q0 + mq*16 + lr) * DM + h*64 + ks*32 + lg*8);

    f32x4 acc[2][16];
#pragma unroll
    for (int nk = 0; nk < 16; ++nk) {
        const int sk = w*256 + nk*16 + lr;
        const u16* kb = Kp + (size_t)(b*S + sk) * DM + h*64 + lg*8;
        s16x8 kf0 = *(const s16x8*)(kb);
        s16x8 kf1 = *(const s16x8*)(kb + 32);
        f32x4 c0 = {};
        c0 = __builtin_amdgcn_mfma_f32_16x16x32_bf16(qf[0][0], kf0, c0, 0, 0, 0);
        c0 = __builtin_amdgcn_mfma_f32_16x16x32_bf16(qf[0][1], kf1, c0, 0, 0, 0);
        acc[0][nk] = c0;
        f32x4 c1 = {};
        c1 = __builtin_amdgcn_mfma_f32_16x16x32_bf16(qf[1][0], kf0, c1, 0, 0, 0);
        c1 = __builtin_amdgcn_mfma_f32_16x16x32_bf16(qf[1][1], kf1, c1, 0, 0, 0);
        acc[1][nk] = c1;
    }

    // scale + mask
    const size_t mbase = (size_t)b * S * S;
#pragma unroll
    for (int mq = 0; mq < 2; ++mq) {
#pragma unroll
        for (int r = 0; r < 4; ++r) {
            const int q = q0 + mq*16 + lg*4 + r;
            const size_t roff = mbase + (size_t)q * S + w*256 + lr;
#pragma unroll
            for (int nk = 0; nk < 16; ++nk) {
                int mv;
                if (mask_bytes) mv = ((const uint8_t*)maskp)[roff + nk*16];
                else            mv = ((const int*)maskp)[roff + nk*16];
                float s = acc[mq][nk][r] * 0.125f;
                acc[mq][nk][r] = mv ? NEGINF : s;
            }
        }
    }

    // row max
    float rmax[2][4];
#pragma unroll
    for (int mq = 0; mq < 2; ++mq)
#pragma unroll
        for (int r = 0; r < 4; ++r) {
            float m = acc[mq][0][r];
#pragma unroll
            for (int nk = 1; nk < 16; ++nk) m = fmaxf(m, acc[mq][nk][r]);
#pragma unroll
            for (int d = 1; d < 16; d <<= 1) m = fmaxf(m, __shfl_xor(m, d, 64));
            rmax[mq][r] = m;
        }
    if (lr == 0) {
#pragma unroll
        for (int mq = 0; mq < 2; ++mq)
#pragma unroll
            for (int r = 0; r < 4; ++r)
                redA[w][mq*16 + lg*4 + r] = rmax[mq][r];
    }
    __syncthreads();
#pragma unroll
    for (int mq = 0; mq < 2; ++mq)
#pragma unroll
        for (int r = 0; r < 4; ++r) {
            const int row = mq*16 + lg*4 + r;
            rmax[mq][r] = fmaxf(fmaxf(redA[0][row], redA[1][row]),
                                fmaxf(redA[2][row], redA[3][row]));
        }

    // exp + row sum
#pragma unroll
    for (int mq = 0; mq < 2; ++mq)
#pragma unroll
        for (int r = 0; r < 4; ++r) {
            float sme = 0.f;
#pragma unroll
            for (int nk = 0; nk < 16; ++nk) {
                float p = __expf(acc[mq][nk][r] - rmax[mq][r]);
                acc[mq][nk][r] = p;
                sme += p;
            }
#pragma unroll
            for (int d = 1; d < 16; d <<= 1) sme += __shfl_xor(sme, d, 64);
            if (lr == 0) redB[w][mq*16 + lg*4 + r] = sme;
        }
    __syncthreads();

    // normalize in place, stash bf16 P in LDS
#pragma unroll
    for (int mq = 0; mq < 2; ++mq)
#pragma unroll
        for (int r = 0; r < 4; ++r) {
            const int row = mq*16 + lg*4 + r;
            const float inv = 1.0f / (redB[0][row] + redB[1][row] + redB[2][row] + redB[3][row]);
#pragma unroll
            for (int nk = 0; nk < 16; ++nk) {
                float p = acc[mq][nk][r] * inv;
                acc[mq][nk][r] = p;
                Plds[row * PLD + w*256 + nk*16 + lr] = f2bf(p);
            }
        }
    __syncthreads();

    // fp32 attn writes (mandatory output) — issued before PV so stores drain under MFMA
    float* ab = attn + (size_t)(b*H + h) * S * S;
#pragma unroll
    for (int mq = 0; mq < 2; ++mq)
#pragma unroll
        for (int r = 0; r < 4; ++r) {
            float* arow = ab + (size_t)(q0 + mq*16 + lg*4 + r) * S + w*256 + lr;
#pragma unroll
            for (int nk = 0; nk < 16; ++nk)
                arow[nk*16] = acc[mq][nk][r];
        }

    // PV: wave w owns d-slice [w*16, w*16+16)
    const u16* vb = Vt + (size_t)(b*H + h) * 64 * S + (size_t)(w*16 + lr) * S;
    f32x4 pacc[2] = {};
    for (int kt = 0; kt < 32; ++kt) {
        const int k0 = kt*32 + lg*8;
        s16x8 vf = *(const s16x8*)(vb + k0);
#pragma unroll
        for (int mq = 0; mq < 2; ++mq) {
            s16x8 af = *(const s16x8*)(Plds + (mq*16 + lr) * PLD + k0);
            pacc[mq] = __builtin_amdgcn_mfma_f32_16x16x32_bf16(af, vf, pacc[mq], 0, 0, 0);
        }
    }
#pragma unroll
    for (int mq = 0; mq < 2; ++mq)
#pragma unroll
        for (int r = 0; r < 4; ++r)
            ctx[(size_t)(b*S + q0 + mq*16 + lg*4 + r) * DM + h*64 + w*16 + lr] = f2bf(pacc[mq][r]);
}

// ---------------- LayerNorm over rows of 1024 ----------------
__global__ __launch_bounds__(256)
void layernorm(const float* __restrict__ x, const float* __restrict__ gamma,
               const float* __restrict__ beta, float* __restrict__ out)
{
    const int row = blockIdx.x;
    const int t = threadIdx.x;
    const float* xr = x + (size_t)row * DM;
    float4 v = *(const float4*)(xr + t*4);
    float s  = v.x + v.y + v.z + v.w;
    float s2 = v.x*v.x + v.y*v.y + v.z*v.z + v.w*v.w;
#pragma unroll
    for (int d = 1; d < 64; d <<= 1) {
        s  += __shfl_xor(s,  d, 64);
        s2 += __shfl_xor(s2, d, 64);
    }
    __shared__ float ls[4], ls2[4];
    if ((t & 63) == 0) { ls[t >> 6] = s; ls2[t >> 6] = s2; }
    __syncthreads();
    s  = ls[0] + ls[1] + ls[2] + ls[3];
    s2 = ls2[0] + ls2[1] + ls2[2] + ls2[3];
    const float mu  = s * (1.0f / DM);
    const float var = s2 * (1.0f / DM) - mu * mu;
    const float rs  = rsqrtf(var + 1e-5f);
    float4 g  = *(const float4*)(gamma + t*4);
    float4 bb = *(const float4*)(beta  + t*4);
    float4 o;
    o.x = (v.x - mu) * rs * g.x + bb.x;
    o.y = (v.y - mu) * rs * g.y + bb.y;
    o.z = (v.z - mu) * rs * g.z + bb.z;
    o.w = (v.w - mu) * rs * g.w + bb.w;
    *(float4*)(out + (size_t)row * DM + t*4) = o;
}

extern "C" void kernel_launch(void* const* d_in, const int* in_sizes, int n_in,
                              void* d_out, int out_size, void* d_ws, size_t ws_size,
                              hipStream_t stream) {
    const float* Qin  = (const float*)d_in[0];
    const float* Kin  = (const float*)d_in[1];
    const float* Vin  = (const float*)d_in[2];
    const void*  mask = d_in[3];
    const float* Wq   = (const float*)d_in[4];
    const float* Wk   = (const float*)d_in[5];
    const float* Wv   = (const float*)d_in[6];
    const float* Wfc  = (const float*)d_in[7];
    const float* gam  = (const float*)d_in[8];
    const float* bet  = (const float*)d_in[9];

    float* out  = (float*)d_out;
    float* attn = (float*)d_out + (size_t)M * DM;

    char* ws = (char*)d_ws;
    constexpr size_t SZ_X = (size_t)M * DM * 2;    // 16 MiB
    constexpr size_t SZ_W = (size_t)DM * DM * 2;   // 2 MiB
    u16* Xq  = (u16*)(ws);
    u16* Xk  = (u16*)(ws + SZ_X);
    u16* Xv  = (u16*)(ws + 2*SZ_X);
    u16* WqT = (u16*)(ws + 3*SZ_X);
    u16* WkT = (u16*)(ws + 3*SZ_X + SZ_W);
    u16* WvT = (u16*)(ws + 3*SZ_X + 2*SZ_W);
    u16* WfT = (u16*)(ws + 3*SZ_X + 3*SZ_W);
    u16* Qp  = (u16*)(ws + 3*SZ_X + 4*SZ_W);
    u16* Kp  = (u16*)(ws + 4*SZ_X + 4*SZ_W);
    u16* Vt  = (u16*)(ws + 5*SZ_X + 4*SZ_W);
    // aliases onto dead buffers:
    float* preLN = (float*)(ws);               // 32 MiB over Xq+Xk (dead after projections)
    u16*   Ctx   = (u16*)(ws + 2*SZ_X);        // 16 MiB over Xv   (dead after V projection)

    dim3 blk(256);
    cvt_all<<<dim3(M * DM / 1024, 3), blk, 0, stream>>>(Qin, Kin, Vin, Xq, Xk, Xv);
    transpose_all<<<dim3(32, 32, 4), blk, 0, stream>>>(Wq, Wk, Wv, Wfc, WqT, WkT, WvT, WfT);

    gemm_bt<0><<<dim3(8, 64), blk, 0, stream>>>(Xq, WqT, Qp, nullptr);
    gemm_bt<0><<<dim3(8, 64), blk, 0, stream>>>(Xk, WkT, Kp, nullptr);
    gemm_bt<1><<<dim3(8, 64), blk, 0, stream>>>(Xv, WvT, Vt, nullptr);

    attn_fused<<<dim3(H, S / 32, B), blk, 0, stream>>>(Qp, Kp, mask, Vt, attn, Ctx);

    gemm_bt<2><<<dim3(8, 64), blk, 0, stream>>>(Ctx, WfT, preLN, Qin);
    layernorm<<<dim3(M), blk, 0, stream>>>(preLN, gam, bet, out);
}

// Round 3
// 546.999 us; speedup vs baseline: 1.2274x; 1.0389x over previous
//
#include <hip/hip_runtime.h>
#include <stdint.h>

typedef unsigned short u16;
typedef float f32x4 __attribute__((ext_vector_type(4)));
typedef short s16x8 __attribute__((ext_vector_type(8)));

constexpr int B  = 8;
constexpr int S  = 1024;
constexpr int DM = 1024;
constexpr int H  = 16;
constexpr int M  = B * S;          // 8192 rows
constexpr float NEGINF = -1e9f;

__device__ __forceinline__ u16 f2bf(float f) {
    union { float f; uint32_t u; } v; v.f = f;
    uint32_t u = v.u;
    uint32_t r = 0x7FFFu + ((u >> 16) & 1u);   // round-to-nearest-even
    return (u16)((u + r) >> 16);
}

// async global->LDS 16B (m97 form): LDS dest = wave-uniform base + lane*16
__device__ __forceinline__ void gload16(const u16* g, u16* l) {
    __builtin_amdgcn_global_load_lds(
        (const __attribute__((address_space(1))) unsigned int*)g,
        (__attribute__((address_space(3))) unsigned int*)l, 16, 0, 0);
}

// ---------------- fp32 -> bf16, all three inputs in one launch ----------------
__global__ void cvt_all(const float* __restrict__ q, const float* __restrict__ k,
                        const float* __restrict__ v,
                        u16* __restrict__ xq, u16* __restrict__ xk, u16* __restrict__ xv) {
    const float* in; u16* out;
    if (blockIdx.y == 0)      { in = q; out = xq; }
    else if (blockIdx.y == 1) { in = k; out = xk; }
    else                      { in = v; out = xv; }
    int i = (blockIdx.x * 256 + threadIdx.x) * 4;
    float4 val = *(const float4*)(in + i);
    ushort4 o;
    o.x = f2bf(val.x); o.y = f2bf(val.y); o.z = f2bf(val.z); o.w = f2bf(val.w);
    *(ushort4*)(out + i) = o;
}

// ---------------- W[k][n] fp32 -> Wt[n][k] bf16, all four weights ----------------
__global__ void transpose_all(const float* __restrict__ w0, const float* __restrict__ w1,
                              const float* __restrict__ w2, const float* __restrict__ w3,
                              u16* __restrict__ o0, u16* __restrict__ o1,
                              u16* __restrict__ o2, u16* __restrict__ o3) {
    const float* W; u16* Wt;
    switch (blockIdx.z) {
        case 0:  W = w0; Wt = o0; break;
        case 1:  W = w1; Wt = o1; break;
        case 2:  W = w2; Wt = o2; break;
        default: W = w3; Wt = o3; break;
    }
    __shared__ float tile[32][33];
    int n0 = blockIdx.x * 32, k0 = blockIdx.y * 32;
    int tx = threadIdx.x & 31, ty = threadIdx.x >> 5;   // 32 x 8
#pragma unroll
    for (int r = 0; r < 4; ++r)
        tile[ty + r*8][tx] = W[(size_t)(k0 + ty + r*8) * DM + n0 + tx];
    __syncthreads();
#pragma unroll
    for (int r = 0; r < 4; ++r)
        Wt[(size_t)(n0 + ty + r*8) * DM + k0 + tx] = f2bf(tile[tx][ty + r*8]);
}

// ---------------- GEMM: C[M x 1024] = A[M x 1024] * Bt[1024 x 1024]^T ----------------
// m97 structure: 128x128 tile, BK=32, global_load_lds width=16, linear LDS.
// EPI 0: C bf16 row-major.  EPI 1: V transposed -> Vt[(b*16+h)*64+d][s].  EPI 2: fp32 + resid.
template<int EPI>
__global__ __launch_bounds__(256, 2)
void gemm_bt(const u16* __restrict__ A, const u16* __restrict__ Bt,
             void* __restrict__ Cv, const float* __restrict__ resid)
{
    __shared__ u16 As[128 * 32];
    __shared__ u16 Bs[128 * 32];
    const int m0 = blockIdx.y * 128;
    const int n0 = blockIdx.x * 128;
    const int t = threadIdx.x;
    const int lane = t & 63;
    const int wid = t >> 6;
    const int wm = (wid >> 1) * 64;
    const int wn = (wid & 1) * 64;
    const int lr = lane & 15;
    const int lg = lane >> 4;

    // thread t stages 16B: LDS element t*8 == row t>>2, col (t&3)*8 of [128][32]
    const u16* Ag = A  + (size_t)(m0 + (t >> 2)) * 1024 + (t & 3) * 8;
    const u16* Bg = Bt + (size_t)(n0 + (t >> 2)) * 1024 + (t & 3) * 8;
    u16* Al = As + t * 8;
    u16* Bl = Bs + t * 8;

    f32x4 acc[4][4] = {};

    for (int kt = 0; kt < 32; ++kt) {
        const int ko = kt * 32;
        __syncthreads();                       // previous compute done
        gload16(Ag + ko,            Al);
        gload16(Ag + 64*1024 + ko,  Al + 64*32);
        gload16(Bg + ko,            Bl);
        gload16(Bg + 64*1024 + ko,  Bl + 64*32);
        __syncthreads();                       // barrier drains vmcnt -> LDS ready
        s16x8 af[4], bfr[4];
#pragma unroll
        for (int m = 0; m < 4; ++m)
            af[m] = *(const s16x8*)(As + (wm + m*16 + lr) * 32 + lg * 8);
#pragma unroll
        for (int n = 0; n < 4; ++n)
            bfr[n] = *(const s16x8*)(Bs + (wn + n*16 + lr) * 32 + lg * 8);
#pragma unroll
        for (int m = 0; m < 4; ++m)
#pragma unroll
            for (int n = 0; n < 4; ++n)
                acc[m][n] = __builtin_amdgcn_mfma_f32_16x16x32_bf16(af[m], bfr[n], acc[m][n], 0, 0, 0);
    }

#pragma unroll
    for (int m = 0; m < 4; ++m) {
#pragma unroll
        for (int n = 0; n < 4; ++n) {
            const int rg0 = m0 + wm + m*16 + lg*4;   // D row = (lane>>4)*4 + reg
            const int cg  = n0 + wn + n*16 + lr;     // D col = lane&15
            if constexpr (EPI == 0) {
                u16* C = (u16*)Cv;
#pragma unroll
                for (int r = 0; r < 4; ++r)
                    C[(size_t)(rg0 + r) * 1024 + cg] = f2bf(acc[m][n][r]);
            } else if constexpr (EPI == 1) {
                u16* C = (u16*)Cv;
                const int bb = rg0 >> 10;
                const int s0 = rg0 & 1023;
                const int hh = cg >> 6;
                const int dd = cg & 63;
                ushort4 pk;
                pk.x = f2bf(acc[m][n][0]); pk.y = f2bf(acc[m][n][1]);
                pk.z = f2bf(acc[m][n][2]); pk.w = f2bf(acc[m][n][3]);
                *(ushort4*)(C + (size_t)((bb*16 + hh)*64 + dd) * 1024 + s0) = pk;
            } else {
                float* C = (float*)Cv;
#pragma unroll
                for (int r = 0; r < 4; ++r) {
                    size_t idx = (size_t)(rg0 + r) * 1024 + cg;
                    C[idx] = acc[m][n][r] + resid[idx];
                }
            }
        }
    }
}

// ---------------- fused scores + softmax + attn-write + PV (swapped QK^T) ----------------
// block: (h, qtile of 16 rows, b); 4 waves; wave w owns k-slice [w*256, w*256+256).
// Swapped MFMA: D[col=lane&15 = q][row = lg*4+r = k] -> each lane holds a full
// q-row slice of P with k contiguous in 4-packs: p[nk][r] <-> k = w*256+nk*16+lg*4+r.
__global__ __launch_bounds__(256, 3)
void attn_fused(const u16* __restrict__ Qp, const u16* __restrict__ Kp,
                const void* __restrict__ maskp, const u16* __restrict__ Vt,
                float* __restrict__ attn, u16* __restrict__ ctx)
{
    const int h  = blockIdx.x;
    const int q0 = blockIdx.y * 16;
    const int b  = blockIdx.z;
    const int t = threadIdx.x;
    const int lane = t & 63;
    const int w = t >> 6;
    const int lr = lane & 15;
    const int lg = lane >> 4;

    __shared__ u16  Pl[4][16][264];     // per-wave P, padded: stride 132 dw == 4 mod 32
    __shared__ float ctxp[4][16][64];   // per-wave partial ctx
    __shared__ float redA[4][16];
    __shared__ float redB[4][16];

    // detect mask dtype: int32 (values 0/1 -> OR<=1) vs packed bytes
    uint32_t orv = 0;
    const uint32_t* mw = (const uint32_t*)maskp;
#pragma unroll
    for (int i = 0; i < 64; ++i) orv |= mw[i];
    const bool mask_bytes = (orv > 1u);

    // Q as B-operand: col=lane&15 -> q = q0+lr; k-dim = d = lg*8+i (+32 for ks=1)
    const u16* qb = Qp + (size_t)(b*S + q0 + lr) * DM + h*64 + lg*8;
    s16x8 qf0 = *(const s16x8*)(qb);
    s16x8 qf1 = *(const s16x8*)(qb + 32);

    // QK^T: A = K rows (16 k-positions per tile)
    f32x4 p[16];
#pragma unroll
    for (int nk = 0; nk < 16; ++nk) {
        const u16* kb = Kp + (size_t)(b*S + w*256 + nk*16 + lr) * DM + h*64 + lg*8;
        s16x8 kf0 = *(const s16x8*)(kb);
        s16x8 kf1 = *(const s16x8*)(kb + 32);
        f32x4 c = {};
        c = __builtin_amdgcn_mfma_f32_16x16x32_bf16(kf0, qf0, c, 0, 0, 0);
        c = __builtin_amdgcn_mfma_f32_16x16x32_bf16(kf1, qf1, c, 0, 0, 0);
        p[nk] = c;
    }

    // mask + scale: lane's values are (q = q0+lr, k = w*256+nk*16+lg*4+{0..3}) -> int4 loads
    const size_t mrow = (size_t)b * S * S + (size_t)(q0 + lr) * S;
#pragma unroll
    for (int nk = 0; nk < 16; ++nk) {
        const size_t off = mrow + w*256 + nk*16 + lg*4;
        int m0, m1, m2, m3;
        if (mask_bytes) {
            uchar4 mb = *(const uchar4*)((const uint8_t*)maskp + off);
            m0 = mb.x; m1 = mb.y; m2 = mb.z; m3 = mb.w;
        } else {
            int4 mi = *(const int4*)((const int*)maskp + off);
            m0 = mi.x; m1 = mi.y; m2 = mi.z; m3 = mi.w;
        }
        p[nk][0] = m0 ? NEGINF : p[nk][0] * 0.125f;
        p[nk][1] = m1 ? NEGINF : p[nk][1] * 0.125f;
        p[nk][2] = m2 ? NEGINF : p[nk][2] * 0.125f;
        p[nk][3] = m3 ? NEGINF : p[nk][3] * 0.125f;
    }

    // row max: vector tree + horizontal + 2 shfl + cross-wave LDS
    f32x4 vm = p[0];
#pragma unroll
    for (int nk = 1; nk < 16; ++nk) {
        vm[0] = fmaxf(vm[0], p[nk][0]); vm[1] = fmaxf(vm[1], p[nk][1]);
        vm[2] = fmaxf(vm[2], p[nk][2]); vm[3] = fmaxf(vm[3], p[nk][3]);
    }
    float hm = fmaxf(fmaxf(vm[0], vm[1]), fmaxf(vm[2], vm[3]));
    hm = fmaxf(hm, __shfl_xor(hm, 16, 64));
    hm = fmaxf(hm, __shfl_xor(hm, 32, 64));
    if (lane < 16) redA[w][lr] = hm;
    __syncthreads();
    const float fm = fmaxf(fmaxf(redA[0][lr], redA[1][lr]),
                           fmaxf(redA[2][lr], redA[3][lr]));

    // exp + row sum
    float hs = 0.f;
#pragma unroll
    for (int nk = 0; nk < 16; ++nk) {
        p[nk][0] = __expf(p[nk][0] - fm);
        p[nk][1] = __expf(p[nk][1] - fm);
        p[nk][2] = __expf(p[nk][2] - fm);
        p[nk][3] = __expf(p[nk][3] - fm);
        hs += p[nk][0] + p[nk][1] + p[nk][2] + p[nk][3];
    }
    hs += __shfl_xor(hs, 16, 64);
    hs += __shfl_xor(hs, 32, 64);
    if (lane < 16) redB[w][lr] = hs;
    __syncthreads();
    const float inv = 1.0f / (redB[0][lr] + redB[1][lr] + redB[2][lr] + redB[3][lr]);

    // normalize; write attn (float4, full lines); stash bf16 packs in per-wave LDS
    float* arow = attn + (size_t)(b*H + h) * S * S + (size_t)(q0 + lr) * S + w*256 + lg*4;
#pragma unroll
    for (int nk = 0; nk < 16; ++nk) {
        p[nk][0] *= inv; p[nk][1] *= inv; p[nk][2] *= inv; p[nk][3] *= inv;
        float4 st; st.x = p[nk][0]; st.y = p[nk][1]; st.z = p[nk][2]; st.w = p[nk][3];
        *(float4*)(arow + nk*16) = st;
        uint2 pk;
        pk.x = (uint32_t)f2bf(p[nk][0]) | ((uint32_t)f2bf(p[nk][1]) << 16);
        pk.y = (uint32_t)f2bf(p[nk][2]) | ((uint32_t)f2bf(p[nk][3]) << 16);
        *(uint2*)&Pl[w][lr][nk*16 + lg*4] = pk;
    }
    __syncthreads();

    // PV over this wave's k-slice: A = P (row=lane&15=q, k=lg*8+i contiguous),
    // B = V (col=lane&15=d-pos, k from Vt[d][s]) -> D[col=lr=d][row=lg*4+r=q]
    const u16* vb = Vt + (size_t)(b*H + h) * 64 * S + w*256 + lg*8;
    f32x4 pacc[4] = {};
#pragma unroll
    for (int kt = 0; kt < 8; ++kt) {
        s16x8 af = *(const s16x8*)&Pl[w][lr][kt*32 + lg*8];
#pragma unroll
        for (int d0 = 0; d0 < 4; ++d0) {
            s16x8 vf = *(const s16x8*)(vb + (size_t)(d0*16 + lr) * S + kt*32);
            pacc[d0] = __builtin_amdgcn_mfma_f32_16x16x32_bf16(af, vf, pacc[d0], 0, 0, 0);
        }
    }
#pragma unroll
    for (int d0 = 0; d0 < 4; ++d0)
#pragma unroll
        for (int r = 0; r < 4; ++r)
            ctxp[w][lg*4 + r][d0*16 + lr] = pacc[d0][r];
    __syncthreads();

    // cross-wave ctx reduce + bf16 store (coalesced)
    {
        const int q  = t >> 4;          // 0..15
        const int d4 = (t & 15) * 4;    // 0..60
        float4 s0 = *(const float4*)&ctxp[0][q][d4];
        float4 s1 = *(const float4*)&ctxp[1][q][d4];
        float4 s2 = *(const float4*)&ctxp[2][q][d4];
        float4 s3 = *(const float4*)&ctxp[3][q][d4];
        float4 sm;
        sm.x = s0.x + s1.x + s2.x + s3.x;
        sm.y = s0.y + s1.y + s2.y + s3.y;
        sm.z = s0.z + s1.z + s2.z + s3.z;
        sm.w = s0.w + s1.w + s2.w + s3.w;
        ushort4 o;
        o.x = f2bf(sm.x); o.y = f2bf(sm.y); o.z = f2bf(sm.z); o.w = f2bf(sm.w);
        *(ushort4*)(ctx + (size_t)(b*S + q0 + q) * DM + h*64 + d4) = o;
    }
}

// ---------------- LayerNorm over rows of 1024 ----------------
__global__ __launch_bounds__(256)
void layernorm(const float* __restrict__ x, const float* __restrict__ gamma,
               const float* __restrict__ beta, float* __restrict__ out)
{
    const int row = blockIdx.x;
    const int t = threadIdx.x;
    const float* xr = x + (size_t)row * DM;
    float4 v = *(const float4*)(xr + t*4);
    float s  = v.x + v.y + v.z + v.w;
    float s2 = v.x*v.x + v.y*v.y + v.z*v.z + v.w*v.w;
#pragma unroll
    for (int d = 1; d < 64; d <<= 1) {
        s  += __shfl_xor(s,  d, 64);
        s2 += __shfl_xor(s2, d, 64);
    }
    __shared__ float ls[4], ls2[4];
    if ((t & 63) == 0) { ls[t >> 6] = s; ls2[t >> 6] = s2; }
    __syncthreads();
    s  = ls[0] + ls[1] + ls[2] + ls[3];
    s2 = ls2[0] + ls2[1] + ls2[2] + ls2[3];
    const float mu  = s * (1.0f / DM);
    const float var = s2 * (1.0f / DM) - mu * mu;
    const float rs  = rsqrtf(var + 1e-5f);
    float4 g  = *(const float4*)(gamma + t*4);
    float4 bb = *(const float4*)(beta  + t*4);
    float4 o;
    o.x = (v.x - mu) * rs * g.x + bb.x;
    o.y = (v.y - mu) * rs * g.y + bb.y;
    o.z = (v.z - mu) * rs * g.z + bb.z;
    o.w = (v.w - mu) * rs * g.w + bb.w;
    *(float4*)(out + (size_t)row * DM + t*4) = o;
}

extern "C" void kernel_launch(void* const* d_in, const int* in_sizes, int n_in,
                              void* d_out, int out_size, void* d_ws, size_t ws_size,
                              hipStream_t stream) {
    const float* Qin  = (const float*)d_in[0];
    const float* Kin  = (const float*)d_in[1];
    const float* Vin  = (const float*)d_in[2];
    const void*  mask = d_in[3];
    const float* Wq   = (const float*)d_in[4];
    const float* Wk   = (const float*)d_in[5];
    const float* Wv   = (const float*)d_in[6];
    const float* Wfc  = (const float*)d_in[7];
    const float* gam  = (const float*)d_in[8];
    const float* bet  = (const float*)d_in[9];

    float* out  = (float*)d_out;
    float* attn = (float*)d_out + (size_t)M * DM;

    char* ws = (char*)d_ws;
    constexpr size_t SZ_X = (size_t)M * DM * 2;    // 16 MiB
    constexpr size_t SZ_W = (size_t)DM * DM * 2;   // 2 MiB
    u16* Xq  = (u16*)(ws);
    u16* Xk  = (u16*)(ws + SZ_X);
    u16* Xv  = (u16*)(ws + 2*SZ_X);
    u16* WqT = (u16*)(ws + 3*SZ_X);
    u16* WkT = (u16*)(ws + 3*SZ_X + SZ_W);
    u16* WvT = (u16*)(ws + 3*SZ_X + 2*SZ_W);
    u16* WfT = (u16*)(ws + 3*SZ_X + 3*SZ_W);
    u16* Qp  = (u16*)(ws + 3*SZ_X + 4*SZ_W);
    u16* Kp  = (u16*)(ws + 4*SZ_X + 4*SZ_W);
    u16* Vt  = (u16*)(ws + 5*SZ_X + 4*SZ_W);
    // aliases onto dead buffers:
    float* preLN = (float*)(ws);               // 32 MiB over Xq+Xk (dead after projections)
    u16*   Ctx   = (u16*)(ws + 2*SZ_X);        // 16 MiB over Xv   (dead after V projection)

    dim3 blk(256);
    cvt_all<<<dim3(M * DM / 1024, 3), blk, 0, stream>>>(Qin, Kin, Vin, Xq, Xk, Xv);
    transpose_all<<<dim3(32, 32, 4), blk, 0, stream>>>(Wq, Wk, Wv, Wfc, WqT, WkT, WvT, WfT);

    gemm_bt<0><<<dim3(8, 64), blk, 0, stream>>>(Xq, WqT, Qp, nullptr);
    gemm_bt<0><<<dim3(8, 64), blk, 0, stream>>>(Xk, WkT, Kp, nullptr);
    gemm_bt<1><<<dim3(8, 64), blk, 0, stream>>>(Xv, WvT, Vt, nullptr);

    attn_fused<<<dim3(H, S / 16, B), blk, 0, stream>>>(Qp, Kp, mask, Vt, attn, Ctx);

    gemm_bt<2><<<dim3(8, 64), blk, 0, stream>>>(Ctx, WfT, preLN, Qin);
    layernorm<<<dim3(M), blk, 0, stream>>>(preLN, gam, bet, out);
}